// Round 18
// baseline (247.025 us; speedup 1.0000x reference)
//
#include <hip/hip_runtime.h>
#include <hip/hip_bf16.h>
#include <stdint.h>

#define NPTS 8192
#define CDIM 128
#define KNNK 16
#define WELEMF 16384               // frag-layout elems per weight image (128*128)
#define SCALE 0.08838834764831845f
#define FLDS_BYTES 78848
#define GRES 8
#define NCELL (GRES*GRES*GRES)

typedef __attribute__((ext_vector_type(4))) float f32x4;
typedef __attribute__((ext_vector_type(8))) short s16x8;

__device__ __forceinline__ unsigned short to_bf16(float f){
  union { __hip_bfloat16 h; unsigned short u; } v;
  v.h = __float2bfloat16(f);
  return v.u;
}

__device__ __forceinline__ s16x8 cvt8(const float* p){
  float4 lo = *(const float4*)p;
  float4 hi = *(const float4*)(p + 4);
  s16x8 f;
  f[0]=(short)to_bf16(lo.x); f[1]=(short)to_bf16(lo.y);
  f[2]=(short)to_bf16(lo.z); f[3]=(short)to_bf16(lo.w);
  f[4]=(short)to_bf16(hi.x); f[5]=(short)to_bf16(hi.y);
  f[6]=(short)to_bf16(hi.z); f[7]=(short)to_bf16(hi.w);
  return f;
}

__device__ __forceinline__ unsigned mapf_u(unsigned s){
  return s ^ (0x80000000u | (unsigned)(((int)s) >> 31));
}
__device__ __forceinline__ float unmapf_u(unsigned u){
  unsigned r = (u & 0x80000000u) ? (u ^ 0x80000000u) : ~u;
  return __uint_as_float(r);
}

// ---------------- setup: gridbuild (blocks 0-1) + weight/x bf16 prep (rest) ----------------
__global__ __launch_bounds__(1024) void setup_kernel(
    const float* __restrict__ pos, float4* __restrict__ spos4,
    int* __restrict__ starts, unsigned* __restrict__ bboxg,
    const float* __restrict__ Wq, const float* __restrict__ Wk,
    const float* __restrict__ Wv, const float* __restrict__ Wp2,
    const float* __restrict__ Wg1, const float* __restrict__ Wg2,
    const float* __restrict__ x,
    unsigned short* __restrict__ wt, unsigned short* __restrict__ xbf)
{
  __shared__ int cnt[NCELL];            // 2 KB (gridbuild blocks only)
  __shared__ int part[1024];            // 4 KB
  __shared__ unsigned bbl[6];
  const int t = threadIdx.x;

  if (blockIdx.x >= 2){
    int bid = blockIdx.x - 2;
    if (bid < 96){                      // weights -> frag-linear bf16 (96*1024 = 6*16384)
      int e = bid*1024 + t;
      int w = e >> 14, f = e & (WELEMF-1);
      int i = f & 7, ln = (f >> 3) & 63, kkct = f >> 9;
      int kk = kkct & 3, ct = kkct >> 2;
      int kdim = kk*32 + (ln >> 4)*8 + i, col = ct*16 + (ln & 15);
      const float* src = (w==0)?Wq:(w==1)?Wk:(w==2)?Wv:(w==3)?Wp2:(w==4)?Wg1:Wg2;
      float v = src[kdim*CDIM + col];
      if (w == 1) v = -v;               // store -Wk so k folds into the t accumulator
      wt[e] = to_bf16(v);
    } else if (xbf){                    // x -> bf16 (256*1024 vec8 = 2*8192*128 elems)
      size_t e = ((size_t)(bid - 96)*1024 + t) * 8;
      s16x8 v = cvt8(x + e);
      *(s16x8*)&xbf[e] = v;
    }
    return;
  }

  // ---- gridbuild: bbox + bin + scan + scatter for batch b ----
  const int b = blockIdx.x;
  for (int i = t; i < NCELL; i += 1024) cnt[i] = 0;
  if (t < 3) bbl[t] = 0xFFFFFFFFu;
  else if (t < 6) bbl[t] = 0u;
  __syncthreads();

  float4 p[8];
  unsigned mn0=~0u, mn1=~0u, mn2=~0u, mx0=0u, mx1=0u, mx2=0u;
#pragma unroll
  for (int i = 0; i < 8; ++i){
    int m = t + i*1024;
    const float* pp = pos + ((size_t)b*NPTS + m)*3;
    float xx = pp[0], yy = pp[1], zz = pp[2];
    float p2 = __fadd_rn(__fadd_rn(__fmul_rn(xx,xx), __fmul_rn(yy,yy)), __fmul_rn(zz,zz));
    p[i] = make_float4(xx, yy, zz, p2);
    unsigned ux = mapf_u(__float_as_uint(xx));
    unsigned uy = mapf_u(__float_as_uint(yy));
    unsigned uz = mapf_u(__float_as_uint(zz));
    mn0 = min(mn0, ux); mn1 = min(mn1, uy); mn2 = min(mn2, uz);
    mx0 = max(mx0, ux); mx1 = max(mx1, uy); mx2 = max(mx2, uz);
  }
#pragma unroll
  for (int off = 1; off < 64; off <<= 1){
    mn0 = min(mn0, (unsigned)__shfl_xor((int)mn0, off));
    mn1 = min(mn1, (unsigned)__shfl_xor((int)mn1, off));
    mn2 = min(mn2, (unsigned)__shfl_xor((int)mn2, off));
    mx0 = max(mx0, (unsigned)__shfl_xor((int)mx0, off));
    mx1 = max(mx1, (unsigned)__shfl_xor((int)mx1, off));
    mx2 = max(mx2, (unsigned)__shfl_xor((int)mx2, off));
  }
  if ((t & 63) == 0){
    atomicMin(&bbl[0], mn0); atomicMin(&bbl[1], mn1); atomicMin(&bbl[2], mn2);
    atomicMax(&bbl[3], mx0); atomicMax(&bbl[4], mx1); atomicMax(&bbl[5], mx2);
  }
  __syncthreads();
  const float lox = unmapf_u(bbl[0]), loy = unmapf_u(bbl[1]), loz = unmapf_u(bbl[2]);
  const float hix = unmapf_u(bbl[3]), hiy = unmapf_u(bbl[4]), hiz = unmapf_u(bbl[5]);

  int cid[8];
#pragma unroll
  for (int i = 0; i < 8; ++i){
    int ix = min(GRES-1, max(0, (int)((p[i].x - lox) * ((float)GRES/(hix-lox)))));
    int iy = min(GRES-1, max(0, (int)((p[i].y - loy) * ((float)GRES/(hiy-loy)))));
    int iz = min(GRES-1, max(0, (int)((p[i].z - loz) * ((float)GRES/(hiz-loz)))));
    cid[i] = (iz*GRES + iy)*GRES + ix;
    atomicAdd(&cnt[cid[i]], 1);
  }
  __syncthreads();
  // exclusive scan of NCELL=512 counts via 1024-wide Hillis-Steele (upper half zero)
  part[t] = (t < NCELL) ? cnt[t] : 0;
  __syncthreads();
  for (int off = 1; off < 1024; off <<= 1){
    int v = (t >= off) ? part[t-off] : 0;
    __syncthreads();
    part[t] += v;
    __syncthreads();
  }
  int* stb = starts + b*(NCELL+1);
  if (t < NCELL){
    int run = (t > 0) ? part[t-1] : 0;
    stb[t] = run;
    cnt[t] = run;                       // cursor
  }
  if (t == NCELL) stb[NCELL] = part[NCELL-1];
  __syncthreads();
  float4* spb = spos4 + ((size_t)b << 13);
#pragma unroll
  for (int i = 0; i < 8; ++i){
    int m = t + i*1024;
    int dst = atomicAdd(&cnt[cid[i]], 1);
    spb[dst] = make_float4(p[i].x, p[i].y, p[i].z, __uint_as_float((unsigned)m));
  }
  if (t < 6) bboxg[b*6 + t] = bbl[t];
}

// ---------------- kNN: 4 queries/wave (16-lane groups), sorted order, ring rows ----------------
__global__ __launch_bounds__(256) void knn_grid_kernel(
    const float4* __restrict__ spos4, const int* __restrict__ starts,
    const unsigned* __restrict__ bbox, int* __restrict__ idxout)
{
  const int tid = threadIdx.x, lane = tid & 63;
  const int sub = lane >> 4, sl = lane & 15, gbase = sub*16;
  const int w = tid >> 6;
  const int g = blockIdx.x*16 + w*4 + sub;          // 16 queries/block (sorted slots)
  const int b = g >> 13, n = g & (NPTS-1);
  const float4* sp = spos4 + ((size_t)b<<13);
  const int*    st = starts + b*(NCELL+1);

  const float4 q4 = sp[n];
  const int orig = __float_as_int(q4.w);
  const float qx = q4.x, qy = q4.y, qz = q4.z;
  const float q2 = __fadd_rn(__fadd_rn(__fmul_rn(qx,qx), __fmul_rn(qy,qy)), __fmul_rn(qz,qz));

  float lox = unmapf_u(bbox[b*6+0]), loy = unmapf_u(bbox[b*6+1]), loz = unmapf_u(bbox[b*6+2]);
  float hix = unmapf_u(bbox[b*6+3]), hiy = unmapf_u(bbox[b*6+4]), hiz = unmapf_u(bbox[b*6+5]);
  float cwx = (hix-lox)*(1.0f/GRES), cwy = (hiy-loy)*(1.0f/GRES), cwz = (hiz-loz)*(1.0f/GRES);
  int cx = min(GRES-1, max(0, (int)((qx - lox) * ((float)GRES/(hix-lox)))));
  int cy = min(GRES-1, max(0, (int)((qy - loy) * ((float)GRES/(hiy-loy)))));
  int cz = min(GRES-1, max(0, (int)((qz - loz) * ((float)GRES/(hiz-loz)))));

  unsigned khi = 0xFFFFFFFFu, klo = 0xFFFFFFFFu;    // per-group sorted list in lanes sl=0..15
  float Tf = __builtin_inff();

  auto insert = [&](unsigned ihi, unsigned ilo){
    unsigned phi = (unsigned)__builtin_amdgcn_update_dpp(0, (int)khi, 0x111, 0xF, 0xF, false);
    unsigned plo = (unsigned)__builtin_amdgcn_update_dpp(0, (int)klo, 0x111, 0xF, 0xF, false);
    bool gt  = (khi > ihi) || (khi == ihi && klo > ilo);
    bool pgt = (sl != 0) && ((phi > ihi) || (phi == ihi && plo > ilo));
    khi = gt ? (pgt ? phi : ihi) : khi;
    klo = gt ? (pgt ? plo : ilo) : klo;
  };
  auto updT = [&](){
    unsigned t15 = (unsigned)__shfl((int)khi, gbase + 15);
    Tf = (t15 >= 0xFF800000u) ? __builtin_inff() : unmapf_u(t15);
  };

  bool gdone = false;
  for (int R = 1; R <= GRES-1; ++R){
    const bool first = (R == 1);
    const int per = 8*R, w1 = 2*R-1;
    const int ntask = first ? 9 : (per + 2*w1*w1);
    for (int tb = 0; tb < ntask; tb += 16){
      int t = tb + sl;
      int dy = 0, dz = 0, gx0 = 0, gx1 = -1;
      bool valid = (!gdone) && (t < ntask);
      if (first){
        if (valid){ dy = t % 3 - 1; dz = t / 3 - 1; }
        gx0 = max(cx-1, 0); gx1 = min(cx+1, GRES-1);
      } else if (valid){
        if (t < per){                       // perimeter rows: full x-range
          int s2 = 2*(2*R+1);
          if (t < s2){ dz = (t < 2*R+1) ? -R : R; dy = t % (2*R+1) - R; }
          else { int u = t - s2; dy = (u & 1) ? R : -R; dz = (u >> 1) - (R-1); }
          gx0 = max(cx-R, 0); gx1 = min(cx+R, GRES-1);
        } else {                            // interior rows: two edge cells
          int i = t - per, ri = i >> 1;
          dy = ri % w1 - (R-1); dz = ri / w1 - (R-1);
          int gx = cx + ((i & 1) ? R : -R);
          gx0 = gx; gx1 = gx;
          valid = gx >= 0 && gx <= GRES-1;
        }
      }
      int gy = cy + dy, gz = cz + dz;
      valid = valid && gy >= 0 && gy < GRES && gz >= 0 && gz < GRES && gx0 <= gx1;
      int s0 = 0, s1 = 0;
      if (valid){ int cb = (gz*GRES + gy)*GRES; s0 = st[cb + gx0]; s1 = st[cb + gx1 + 1]; }
      unsigned long long bal = __ballot(valid && (s1 > s0));
      unsigned cm = (unsigned)((bal >> gbase) & 0xFFFFull);
      while (__any(cm != 0)){
        bool act = (cm != 0);
        int srow = act ? __builtin_ctz(cm) : 0;
        if (act) cm &= cm - 1;
        int cs = __shfl(s0, gbase + srow);
        int ce = __shfl(s1, gbase + srow);
        if (!act){ cs = 0; ce = 0; }
        for (int p0 = cs; p0 < ce; p0 += 16){
          int mm = p0 + sl;
          bool v = mm < ce;
          float4 c = v ? sp[mm] : make_float4(0.f,0.f,0.f,0.f);
          float c2  = __fadd_rn(__fadd_rn(__fmul_rn(c.x,c.x), __fmul_rn(c.y,c.y)), __fmul_rn(c.z,c.z));
          float dot = __builtin_fmaf(c.z, qz, __builtin_fmaf(c.y, qy, __fmul_rn(c.x, qx)));
          float d2  = __fsub_rn(__fadd_rn(q2, c2), __fadd_rn(dot, dot));
          int oi = __float_as_int(c.w);
          bool ins = v && (d2 <= Tf);
          unsigned long long ib = __ballot(ins);
          unsigned im = (unsigned)((ib >> gbase) & 0xFFFFull);
          if (__any(im != 0)){
            while (__any(im != 0)){
              bool a2 = (im != 0);
              int s = a2 ? __builtin_ctz(im) : 0;
              if (a2) im &= im - 1;
              unsigned dvb = (unsigned)__shfl((int)__float_as_uint(d2), gbase + s);
              int ov = __shfl(oi, gbase + s);
              if (a2) insert(mapf_u(dvb), (unsigned)ov);
            }
            updT();
          }
        }
      }
    }
    const float big = 1e30f;
    float dxlo = (cx-R <= 0)      ? big : (qx - (lox + (float)(cx-R)*cwx));
    float dxhi = (cx+R >= GRES-1) ? big : ((lox + (float)(cx+R+1)*cwx) - qx);
    float dylo = (cy-R <= 0)      ? big : (qy - (loy + (float)(cy-R)*cwy));
    float dyhi = (cy+R >= GRES-1) ? big : ((loy + (float)(cy+R+1)*cwy) - qy);
    float dzlo = (cz-R <= 0)      ? big : (qz - (loz + (float)(cz-R)*cwz));
    float dzhi = (cz+R >= GRES-1) ? big : ((loz + (float)(cz+R+1)*cwz) - qz);
    float dmin = fminf(fminf(fminf(dxlo,dxhi), fminf(dylo,dyhi)), fminf(dzlo,dzhi));
    bool full = dmin >= 1e29f;
    dmin = fmaxf(dmin, 0.0f);
    float dmin2 = dmin*dmin;
    bool stop = full || (Tf + 1e-4f + Tf*1e-5f < dmin2);
    gdone = gdone || stop;
    if (__all(gdone)) break;
  }
  idxout[(((size_t)b<<13) + orig)*KNNK + sl] = (int)klo;
}

// ---------------- fused transform: 512 thr / 16 points, dual-buffer + gll + seq tiles ----------------
__global__ __launch_bounds__(512, 2) void fused_kernel(
    const float* __restrict__ x, const float* __restrict__ pos,
    const float* __restrict__ bq, const float* __restrict__ bk,
    const float* __restrict__ bv, const float* __restrict__ Wp1,
    const float* __restrict__ bp1, const float* __restrict__ bp2,
    const float* __restrict__ bg1, const float* __restrict__ bg2,
    const int* __restrict__ idxws, const unsigned short* __restrict__ wt,
    const unsigned short* __restrict__ xbf,
    float* __restrict__ out)
{
  extern __shared__ char smem[];
  char* Sbase = smem;                                        // weight slot S: 32768 B
  char* Tbase = smem + 32768;                                // weight slot T / per-wave tiles: 32768 B
  float* blds = (float*)(smem + 65536);                      // 1280 f32 = 5120 B
  float* q_lds = (float*)(smem + 70656);                     // [16][128] f32 = 8192 B (total 78848)

  const int tid = threadIdx.x;
  const int lane = tid & 63, w = tid >> 6;                   // w = 0..7
  const int r = lane & 15, grp = lane >> 4;
  const int pbase = blockIdx.x * 16;
  const int b = pbase >> 13;

  auto gll = [&](int s, char* dst){
#pragma unroll
    for (int k = 0; k < 4; ++k){
      int c = w*4 + k;
      unsigned short* g = const_cast<unsigned short*>(wt) + (size_t)s*WELEMF + c*512 + lane*8;
      __builtin_amdgcn_global_load_lds(
        (const __attribute__((address_space(1))) void*)g,
        (__attribute__((address_space(3))) void*)(dst + c*1024), 16, 0, 0);
    }
  };
  auto ldS = [&](int ct, int kk) -> s16x8 {
    return *(const s16x8*)&((unsigned short*)Sbase)[((ct*4 + kk)*64 + lane)*8];
  };
  auto ldT = [&](int ct, int kk) -> s16x8 {
    return *(const s16x8*)&((unsigned short*)Tbase)[((ct*4 + kk)*64 + lane)*8];
  };

  gll(0, Sbase);   // Wq  -> S  (cold)
  gll(3, Tbase);   // Wp2 -> T  (cold)

  for (int e = tid; e < 1280; e += 512){
    float v;
    if      (e < 128)  v = bq[e];
    else if (e < 256)  v = bk[e-128];
    else if (e < 384)  v = bv[e-256];
    else if (e < 512)  v = bp2[e-384];
    else if (e < 640)  v = bg1[e-512];
    else if (e < 768)  v = bg2[e-640];
    else if (e < 896)  v = bp1[e-768];
    else               v = Wp1[e-896];
    blds[e] = v;
  }
  int nbr[2]; float relx[2], rely[2], relz[2];
#pragma unroll
  for (int j = 0; j < 2; ++j){
    int gp = pbase + w*2 + j;
    nbr[j] = idxws[(size_t)gp*KNNK + r];
    const float* pq = pos + (size_t)gp*3;
    const float* pn = pos + ((size_t)b*NPTS + nbr[j])*3;
    relx[j] = pq[0]-pn[0]; rely[j] = pq[1]-pn[1]; relz[j] = pq[2]-pn[2];
  }
  s16x8 qa[4];
  if (xbf){
    const unsigned short* xr = xbf + (size_t)(pbase + r)*CDIM;
#pragma unroll
    for (int kk = 0; kk < 4; ++kk) qa[kk] = *(const s16x8*)&xr[kk*32 + grp*8];
  } else {
    const float* xr = x + (size_t)(pbase + r)*CDIM;
#pragma unroll
    for (int kk = 0; kk < 4; ++kk) qa[kk] = cvt8(xr + kk*32 + grp*8);
  }
  __syncthreads();   // Wq(S), Wp2(T), blds visible

  // ---- q = x@Wq + bq from S: wave w computes column tile ct = w ----
  {
    f32x4 qacc = (f32x4){0.f,0.f,0.f,0.f};
#pragma unroll
    for (int kk = 0; kk < 4; ++kk)
      qacc = __builtin_amdgcn_mfma_f32_16x16x32_bf16(qa[kk], ldS(w,kk), qacc, 0,0,0);
    int col = w*16 + r;
#pragma unroll
    for (int jj = 0; jj < 4; ++jj){
      int row = grp*4 + jj;
      q_lds[row*CDIM + col] = qacc[jj] + blds[col];
    }
  }
  // ---- pe1 = relu(rel@Wp1 + bp1) in A-frag layout ----
  s16x8 pf[2][4];
#pragma unroll
  for (int j = 0; j < 2; ++j)
#pragma unroll
    for (int kk = 0; kk < 4; ++kk){
      s16x8 f;
#pragma unroll
      for (int i = 0; i < 8; ++i){
        int kc = kk*32 + grp*8 + i;
        float s = relx[j]*blds[896+kc] + rely[j]*blds[1024+kc] + relz[j]*blds[1152+kc] + blds[768+kc];
        f[i] = (short)to_bf16(fmaxf(s, 0.f));
      }
      pf[j][kk] = f;
    }
  __syncthreads();   // Wq consumed; q_lds visible
  gll(1, Sbase);     // -Wk -> S, hides under pe1@Wp2 MFMAs

  f32x4 at[2][8], av[2][8];
#pragma unroll
  for (int j=0;j<2;++j)
#pragma unroll
    for (int ct=0;ct<8;++ct) at[j][ct] = (f32x4){0.f,0.f,0.f,0.f};
#pragma unroll
  for (int ct=0;ct<8;++ct)
#pragma unroll
    for (int kk=0;kk<4;++kk){
      s16x8 bw = ldT(ct,kk);
#pragma unroll
      for (int j=0;j<2;++j)
        at[j][ct] = __builtin_amdgcn_mfma_f32_16x16x32_bf16(pf[j][kk], bw, at[j][ct], 0,0,0);
    }
  s16x8 nf[2][4];
  if (xbf){
#pragma unroll
    for (int j=0;j<2;++j){
      const unsigned short* xr = xbf + ((size_t)b*NPTS + nbr[j])*CDIM;
#pragma unroll
      for (int kk=0;kk<4;++kk)
        nf[j][kk] = *(const s16x8*)&xr[kk*32 + grp*8];
    }
  } else {
#pragma unroll
    for (int j=0;j<2;++j)
#pragma unroll
      for (int kk=0;kk<4;++kk)
        nf[j][kk] = cvt8(x + ((size_t)b*NPTS + nbr[j])*CDIM + kk*32 + grp*8);
  }

  __syncthreads();   // Wp2 consumed; -Wk visible
  gll(2, Tbase);     // Wv -> T, hides under nf@(-Wk) MFMAs
#pragma unroll
  for (int j=0;j<2;++j)
#pragma unroll
    for (int ct=0;ct<8;++ct) av[j][ct] = at[j][ct];
#pragma unroll
  for (int ct=0;ct<8;++ct)
#pragma unroll
    for (int kk=0;kk<4;++kk){
      s16x8 bw = ldS(ct,kk);
#pragma unroll
      for (int j=0;j<2;++j) at[j][ct] = __builtin_amdgcn_mfma_f32_16x16x32_bf16(nf[j][kk], bw, at[j][ct], 0,0,0);
    }
  __syncthreads();   // -Wk consumed; Wv visible
  gll(4, Sbase);     // Wg1 -> S, hides under nf@Wv MFMAs
#pragma unroll
  for (int ct=0;ct<8;++ct)
#pragma unroll
    for (int kk=0;kk<4;++kk){
      s16x8 bw = ldT(ct,kk);
#pragma unroll
      for (int j=0;j<2;++j) av[j][ct] = __builtin_amdgcn_mfma_f32_16x16x32_bf16(nf[j][kk], bw, av[j][ct], 0,0,0);
    }
  // t = (q - k + pe) * scale
#pragma unroll
  for (int j=0;j<2;++j){
    int prow = (w*2+j)*CDIM;
#pragma unroll
    for (int ct=0;ct<8;++ct){
      int col = ct*16+r;
      float add = q_lds[prow+col] + blds[384+col] - blds[128+col];
#pragma unroll
      for (int jj=0;jj<4;++jj) at[j][ct][jj] = (at[j][ct][jj] + add)*SCALE;
    }
  }
  __syncthreads();   // Wv consumed (T freed for per-wave tiles); Wg1 visible

  // ---- gating MLP: per-wave private 4KB tile, points processed sequentially ----
  unsigned short* tj = (unsigned short*)Tbase + w*2048;      // 8 waves x 4KB = 32KB
  s16x8 tf[2][4];
#pragma unroll
  for (int j=0;j<2;++j){
#pragma unroll
    for (int ct=0;ct<8;++ct){
      int base = (ct>>1)*512 + ((ct&1)*2 + (r>>3))*128 + (r&7);
#pragma unroll
      for (int jj=0;jj<4;++jj)
        tj[base + (grp*4+jj)*8] = to_bf16(at[j][ct][jj]);
    }
#pragma unroll
    for (int kk=0;kk<4;++kk)
      tf[j][kk] = *(const s16x8*)&tj[(kk*64 + lane)*8];
  }
  f32x4 hacc[2][8];
#pragma unroll
  for (int j=0;j<2;++j)
#pragma unroll
    for (int ct=0;ct<8;++ct) hacc[j][ct] = (f32x4){0.f,0.f,0.f,0.f};
#pragma unroll
  for (int ct=0;ct<8;++ct)
#pragma unroll
    for (int kk=0;kk<4;++kk){
      s16x8 bw = ldS(ct,kk);
#pragma unroll
      for (int j=0;j<2;++j)
        hacc[j][ct] = __builtin_amdgcn_mfma_f32_16x16x32_bf16(tf[j][kk], bw, hacc[j][ct], 0,0,0);
    }
  __syncthreads();   // Wg1 consumed
  gll(5, Sbase);     // Wg2 -> S, hides under relu tile write/read
  s16x8 hf[2][4];
#pragma unroll
  for (int j=0;j<2;++j){
#pragma unroll
    for (int ct=0;ct<8;++ct){
      int base = (ct>>1)*512 + ((ct&1)*2 + (r>>3))*128 + (r&7);
      int col = ct*16+r; float bb = blds[512+col];
#pragma unroll
      for (int jj=0;jj<4;++jj)
        tj[base + (grp*4+jj)*8] = to_bf16(fmaxf(hacc[j][ct][jj]+bb, 0.f));
    }
#pragma unroll
    for (int kk=0;kk<4;++kk)
      hf[j][kk] = *(const s16x8*)&tj[(kk*64 + lane)*8];
  }
  __syncthreads();   // Wg2 visible
  f32x4 gacc[2][8];
#pragma unroll
  for (int j=0;j<2;++j)
#pragma unroll
    for (int ct=0;ct<8;++ct) gacc[j][ct] = (f32x4){0.f,0.f,0.f,0.f};
#pragma unroll
  for (int ct=0;ct<8;++ct)
#pragma unroll
    for (int kk=0;kk<4;++kk){
      s16x8 bw = ldS(ct,kk);
#pragma unroll
      for (int j=0;j<2;++j)
        gacc[j][ct] = __builtin_amdgcn_mfma_f32_16x16x32_bf16(hf[j][kk], bw, gacc[j][ct], 0,0,0);
    }
#pragma unroll
  for (int j=0;j<2;++j){
#pragma unroll
    for (int ct=0;ct<8;++ct){
      int col = ct*16+r;
      float gb = blds[640+col];
      float g0v = gacc[j][ct][0]+gb, g1v = gacc[j][ct][1]+gb;
      float g2v = gacc[j][ct][2]+gb, g3v = gacc[j][ct][3]+gb;
      float mx = fmaxf(fmaxf(g0v,g1v), fmaxf(g2v,g3v));
      mx = fmaxf(mx, __shfl_xor(mx,16));
      mx = fmaxf(mx, __shfl_xor(mx,32));
      float e0=__expf(g0v-mx), e1=__expf(g1v-mx), e2=__expf(g2v-mx), e3=__expf(g3v-mx);
      float vb = blds[256+col] + blds[384+col];
      float ss = e0+e1+e2+e3;
      float oo = e0*(av[j][ct][0]+vb) + e1*(av[j][ct][1]+vb)
               + e2*(av[j][ct][2]+vb) + e3*(av[j][ct][3]+vb);
      ss += __shfl_xor(ss,16); ss += __shfl_xor(ss,32);
      oo += __shfl_xor(oo,16); oo += __shfl_xor(oo,32);
      if (grp == 0) out[(size_t)(pbase + w*2 + j)*CDIM + col] = oo/ss;
    }
  }
}

extern "C" void kernel_launch(void* const* d_in, const int* in_sizes, int n_in,
                              void* d_out, int out_size, void* d_ws, size_t ws_size,
                              hipStream_t stream)
{
  const float* x    = (const float*)d_in[0];
  const float* pos  = (const float*)d_in[1];
  const float* Wq   = (const float*)d_in[2];
  const float* bq   = (const float*)d_in[3];
  const float* Wk   = (const float*)d_in[4];
  const float* bk   = (const float*)d_in[5];
  const float* Wv   = (const float*)d_in[6];
  const float* bv   = (const float*)d_in[7];
  const float* Wp1  = (const float*)d_in[8];
  const float* bp1  = (const float*)d_in[9];
  const float* Wp2  = (const float*)d_in[10];
  const float* bp2  = (const float*)d_in[11];
  const float* Wg1  = (const float*)d_in[12];
  const float* bg1  = (const float*)d_in[13];
  const float* Wg2  = (const float*)d_in[14];
  const float* bg2  = (const float*)d_in[15];
  float* out = (float*)d_out;

  char* ws = (char*)d_ws;
  int*            idxs   = (int*)ws;                          // 1,048,576
  unsigned short* wt     = (unsigned short*)(ws + 1048576);   //   196,608 (frag layout)
  float4*         spos4  = (float4*)(ws + 1519616);           //   262,144
  int*            starts = (int*)(ws + 2174976);              //     4,104
  unsigned*       bbox   = (unsigned*)(ws + 2699520);         //        48
  const size_t XBF_OFF = 2699776;
  const size_t XBF_SZ  = (size_t)2*NPTS*CDIM*2;               // 4,194,304
  unsigned short* xbf = (ws_size >= XBF_OFF + XBF_SZ) ? (unsigned short*)(ws + XBF_OFF) : nullptr;

  hipFuncSetAttribute((const void*)fused_kernel,
                      hipFuncAttributeMaxDynamicSharedMemorySize, FLDS_BYTES);

  setup_kernel<<<xbf ? 354 : 98, 1024, 0, stream>>>(pos, spos4, starts, bbox,
                                                    Wq, Wk, Wv, Wp2, Wg1, Wg2, x, wt, xbf);
  knn_grid_kernel<<<1024, 256, 0, stream>>>(spos4, starts, bbox, idxs);
  fused_kernel<<<1024, 512, FLDS_BYTES, stream>>>(x, pos, bq, bk, bv, Wp1, bp1, bp2,
                                                  bg1, bg2, idxs, wt, xbf, out);
}

// Round 19
// 181.548 us; speedup vs baseline: 1.3607x; 1.3607x over previous
//
#include <hip/hip_runtime.h>
#include <hip/hip_bf16.h>
#include <stdint.h>

#define NPTS 8192
#define CDIM 128
#define KNNK 16
#define WELEMF 16384               // frag-layout elems per weight image (128*128)
#define SCALE 0.08838834764831845f
#define FLDS_BYTES 78848
#define GRES 16
#define NCELL (GRES*GRES*GRES)

typedef __attribute__((ext_vector_type(4))) float f32x4;
typedef __attribute__((ext_vector_type(8))) short s16x8;

__device__ __forceinline__ unsigned short to_bf16(float f){
  union { __hip_bfloat16 h; unsigned short u; } v;
  v.h = __float2bfloat16(f);
  return v.u;
}

__device__ __forceinline__ s16x8 cvt8(const float* p){
  float4 lo = *(const float4*)p;
  float4 hi = *(const float4*)(p + 4);
  s16x8 f;
  f[0]=(short)to_bf16(lo.x); f[1]=(short)to_bf16(lo.y);
  f[2]=(short)to_bf16(lo.z); f[3]=(short)to_bf16(lo.w);
  f[4]=(short)to_bf16(hi.x); f[5]=(short)to_bf16(hi.y);
  f[6]=(short)to_bf16(hi.z); f[7]=(short)to_bf16(hi.w);
  return f;
}

__device__ __forceinline__ unsigned mapf_u(unsigned s){
  return s ^ (0x80000000u | (unsigned)(((int)s) >> 31));
}
__device__ __forceinline__ float unmapf_u(unsigned u){
  unsigned r = (u & 0x80000000u) ? (u ^ 0x80000000u) : ~u;
  return __uint_as_float(r);
}

// ---------------- setup: gridbuild (blocks 0-1) + weight/x bf16 prep (rest) ----------------
// Independent jobs fused into one launch so gridbuild's 2 fat blocks overlap the
// 352 light conversion blocks instead of serializing before them.
__global__ __launch_bounds__(1024) void setup_kernel(
    const float* __restrict__ pos, float4* __restrict__ spos4,
    int* __restrict__ starts, unsigned* __restrict__ bboxg,
    const float* __restrict__ Wq, const float* __restrict__ Wk,
    const float* __restrict__ Wv, const float* __restrict__ Wp2,
    const float* __restrict__ Wg1, const float* __restrict__ Wg2,
    const float* __restrict__ x,
    unsigned short* __restrict__ wt, unsigned short* __restrict__ xbf)
{
  __shared__ int cnt[NCELL];            // 16 KB (used by gridbuild blocks only)
  __shared__ int part[1024];            // 4 KB
  __shared__ unsigned bbl[6];
  const int t = threadIdx.x;

  if (blockIdx.x >= 2){
    int bid = blockIdx.x - 2;
    if (bid < 96){                      // weights -> frag-linear bf16 (96*1024 = 6*16384)
      int e = bid*1024 + t;
      int w = e >> 14, f = e & (WELEMF-1);
      int i = f & 7, ln = (f >> 3) & 63, kkct = f >> 9;
      int kk = kkct & 3, ct = kkct >> 2;
      int kdim = kk*32 + (ln >> 4)*8 + i, col = ct*16 + (ln & 15);
      const float* src = (w==0)?Wq:(w==1)?Wk:(w==2)?Wv:(w==3)?Wp2:(w==4)?Wg1:Wg2;
      float v = src[kdim*CDIM + col];
      if (w == 1) v = -v;               // store -Wk so k folds into the t accumulator
      wt[e] = to_bf16(v);
    } else if (xbf){                    // x -> bf16 (256*1024 vec8 = 2*8192*128 elems)
      size_t e = ((size_t)(bid - 96)*1024 + t) * 8;
      s16x8 v = cvt8(x + e);
      *(s16x8*)&xbf[e] = v;
    }
    return;
  }

  // ---- gridbuild: bbox + bin + scan + scatter for batch b ----
  const int b = blockIdx.x;
  for (int i = t; i < NCELL; i += 1024) cnt[i] = 0;
  if (t < 3) bbl[t] = 0xFFFFFFFFu;
  else if (t < 6) bbl[t] = 0u;
  __syncthreads();

  float4 p[8];
  unsigned mn0=~0u, mn1=~0u, mn2=~0u, mx0=0u, mx1=0u, mx2=0u;
#pragma unroll
  for (int i = 0; i < 8; ++i){
    int m = t + i*1024;
    const float* pp = pos + ((size_t)b*NPTS + m)*3;
    float xx = pp[0], yy = pp[1], zz = pp[2];
    float p2 = __fadd_rn(__fadd_rn(__fmul_rn(xx,xx), __fmul_rn(yy,yy)), __fmul_rn(zz,zz));
    p[i] = make_float4(xx, yy, zz, p2);
    unsigned ux = mapf_u(__float_as_uint(xx));
    unsigned uy = mapf_u(__float_as_uint(yy));
    unsigned uz = mapf_u(__float_as_uint(zz));
    mn0 = min(mn0, ux); mn1 = min(mn1, uy); mn2 = min(mn2, uz);
    mx0 = max(mx0, ux); mx1 = max(mx1, uy); mx2 = max(mx2, uz);
  }
#pragma unroll
  for (int off = 1; off < 64; off <<= 1){
    mn0 = min(mn0, (unsigned)__shfl_xor((int)mn0, off));
    mn1 = min(mn1, (unsigned)__shfl_xor((int)mn1, off));
    mn2 = min(mn2, (unsigned)__shfl_xor((int)mn2, off));
    mx0 = max(mx0, (unsigned)__shfl_xor((int)mx0, off));
    mx1 = max(mx1, (unsigned)__shfl_xor((int)mx1, off));
    mx2 = max(mx2, (unsigned)__shfl_xor((int)mx2, off));
  }
  if ((t & 63) == 0){
    atomicMin(&bbl[0], mn0); atomicMin(&bbl[1], mn1); atomicMin(&bbl[2], mn2);
    atomicMax(&bbl[3], mx0); atomicMax(&bbl[4], mx1); atomicMax(&bbl[5], mx2);
  }
  __syncthreads();
  const float lox = unmapf_u(bbl[0]), loy = unmapf_u(bbl[1]), loz = unmapf_u(bbl[2]);
  const float hix = unmapf_u(bbl[3]), hiy = unmapf_u(bbl[4]), hiz = unmapf_u(bbl[5]);

  int cid[8];
#pragma unroll
  for (int i = 0; i < 8; ++i){
    int ix = min(GRES-1, max(0, (int)((p[i].x - lox) * ((float)GRES/(hix-lox)))));
    int iy = min(GRES-1, max(0, (int)((p[i].y - loy) * ((float)GRES/(hiy-loy)))));
    int iz = min(GRES-1, max(0, (int)((p[i].z - loz) * ((float)GRES/(hiz-loz)))));
    cid[i] = (iz*GRES + iy)*GRES + ix;
    atomicAdd(&cnt[cid[i]], 1);
  }
  __syncthreads();
  // exclusive scan of 4096 counts: 4/thread + 1024-wide Hillis-Steele
  const int base = t*4;
  int c0 = cnt[base], c1 = cnt[base+1], c2 = cnt[base+2], c3 = cnt[base+3];
  part[t] = c0+c1+c2+c3;
  __syncthreads();
  for (int off = 1; off < 1024; off <<= 1){
    int v = (t >= off) ? part[t-off] : 0;
    __syncthreads();
    part[t] += v;
    __syncthreads();
  }
  int run = (t > 0) ? part[t-1] : 0;
  int* stb = starts + b*(NCELL+1);
  int r1 = run + c0, r2 = r1 + c1, r3 = r2 + c2;
  stb[base] = run; stb[base+1] = r1; stb[base+2] = r2; stb[base+3] = r3;
  if (t == 1023) stb[NCELL] = r3 + c3;
  cnt[base] = run; cnt[base+1] = r1; cnt[base+2] = r2; cnt[base+3] = r3;  // cursor
  __syncthreads();
  float4* spb = spos4 + ((size_t)b << 13);
#pragma unroll
  for (int i = 0; i < 8; ++i){
    int m = t + i*1024;
    int dst = atomicAdd(&cnt[cid[i]], 1);
    spb[dst] = make_float4(p[i].x, p[i].y, p[i].z, __uint_as_float((unsigned)m));
  }
  if (t < 6) bboxg[b*6 + t] = bbl[t];
}

// ---------------- kNN: 4 queries/wave (16-lane groups), sorted order, ring rows ----------------
__global__ __launch_bounds__(256) void knn_grid_kernel(
    const float4* __restrict__ spos4, const int* __restrict__ starts,
    const unsigned* __restrict__ bbox, int* __restrict__ idxout)
{
  const int tid = threadIdx.x, lane = tid & 63;
  const int sub = lane >> 4, sl = lane & 15, gbase = sub*16;
  const int w = tid >> 6;
  const int g = blockIdx.x*16 + w*4 + sub;          // 16 queries/block (sorted slots)
  const int b = g >> 13, n = g & (NPTS-1);
  const float4* sp = spos4 + ((size_t)b<<13);
  const int*    st = starts + b*(NCELL+1);

  const float4 q4 = sp[n];
  const int orig = __float_as_int(q4.w);
  const float qx = q4.x, qy = q4.y, qz = q4.z;
  const float q2 = __fadd_rn(__fadd_rn(__fmul_rn(qx,qx), __fmul_rn(qy,qy)), __fmul_rn(qz,qz));

  float lox = unmapf_u(bbox[b*6+0]), loy = unmapf_u(bbox[b*6+1]), loz = unmapf_u(bbox[b*6+2]);
  float hix = unmapf_u(bbox[b*6+3]), hiy = unmapf_u(bbox[b*6+4]), hiz = unmapf_u(bbox[b*6+5]);
  float cwx = (hix-lox)*(1.0f/GRES), cwy = (hiy-loy)*(1.0f/GRES), cwz = (hiz-loz)*(1.0f/GRES);
  int cx = min(GRES-1, max(0, (int)((qx - lox) * ((float)GRES/(hix-lox)))));
  int cy = min(GRES-1, max(0, (int)((qy - loy) * ((float)GRES/(hiy-loy)))));
  int cz = min(GRES-1, max(0, (int)((qz - loz) * ((float)GRES/(hiz-loz)))));

  unsigned khi = 0xFFFFFFFFu, klo = 0xFFFFFFFFu;    // per-group sorted list in lanes sl=0..15
  float Tf = __builtin_inff();

  auto insert = [&](unsigned ihi, unsigned ilo){
    unsigned phi = (unsigned)__builtin_amdgcn_update_dpp(0, (int)khi, 0x111, 0xF, 0xF, false);
    unsigned plo = (unsigned)__builtin_amdgcn_update_dpp(0, (int)klo, 0x111, 0xF, 0xF, false);
    bool gt  = (khi > ihi) || (khi == ihi && klo > ilo);
    bool pgt = (sl != 0) && ((phi > ihi) || (phi == ihi && plo > ilo));
    khi = gt ? (pgt ? phi : ihi) : khi;
    klo = gt ? (pgt ? plo : ilo) : klo;
  };
  auto updT = [&](){
    unsigned t15 = (unsigned)__shfl((int)khi, gbase + 15);
    Tf = (t15 >= 0xFF800000u) ? __builtin_inff() : unmapf_u(t15);
  };

  bool gdone = false;
  for (int R = 1; R <= GRES-1; ++R){
    const bool first = (R == 1);
    const int per = 8*R, w1 = 2*R-1;
    const int ntask = first ? 9 : (per + 2*w1*w1);
    for (int tb = 0; tb < ntask; tb += 16){
      int t = tb + sl;
      int dy = 0, dz = 0, gx0 = 0, gx1 = -1;
      bool valid = (!gdone) && (t < ntask);
      if (first){
        if (valid){ dy = t % 3 - 1; dz = t / 3 - 1; }
        gx0 = max(cx-1, 0); gx1 = min(cx+1, GRES-1);
      } else if (valid){
        if (t < per){                       // perimeter rows: full x-range
          int s2 = 2*(2*R+1);
          if (t < s2){ dz = (t < 2*R+1) ? -R : R; dy = t % (2*R+1) - R; }
          else { int u = t - s2; dy = (u & 1) ? R : -R; dz = (u >> 1) - (R-1); }
          gx0 = max(cx-R, 0); gx1 = min(cx+R, GRES-1);
        } else {                            // interior rows: two edge cells
          int i = t - per, ri = i >> 1;
          dy = ri % w1 - (R-1); dz = ri / w1 - (R-1);
          int gx = cx + ((i & 1) ? R : -R);
          gx0 = gx; gx1 = gx;
          valid = gx >= 0 && gx <= GRES-1;
        }
      }
      int gy = cy + dy, gz = cz + dz;
      valid = valid && gy >= 0 && gy < GRES && gz >= 0 && gz < GRES && gx0 <= gx1;
      int s0 = 0, s1 = 0;
      if (valid){ int cb = (gz*GRES + gy)*GRES; s0 = st[cb + gx0]; s1 = st[cb + gx1 + 1]; }
      unsigned long long bal = __ballot(valid && (s1 > s0));
      unsigned cm = (unsigned)((bal >> gbase) & 0xFFFFull);
      while (__any(cm != 0)){
        bool act = (cm != 0);
        int srow = act ? __builtin_ctz(cm) : 0;
        if (act) cm &= cm - 1;
        int cs = __shfl(s0, gbase + srow);
        int ce = __shfl(s1, gbase + srow);
        if (!act){ cs = 0; ce = 0; }
        for (int p0 = cs; p0 < ce; p0 += 16){
          int mm = p0 + sl;
          bool v = mm < ce;
          float4 c = v ? sp[mm] : make_float4(0.f,0.f,0.f,0.f);
          float c2  = __fadd_rn(__fadd_rn(__fmul_rn(c.x,c.x), __fmul_rn(c.y,c.y)), __fmul_rn(c.z,c.z));
          float dot = __builtin_fmaf(c.z, qz, __builtin_fmaf(c.y, qy, __fmul_rn(c.x, qx)));
          float d2  = __fsub_rn(__fadd_rn(q2, c2), __fadd_rn(dot, dot));
          int oi = __float_as_int(c.w);
          bool ins = v && (d2 <= Tf);
          unsigned long long ib = __ballot(ins);
          unsigned im = (unsigned)((ib >> gbase) & 0xFFFFull);
          if (__any(im != 0)){
            while (__any(im != 0)){
              bool a2 = (im != 0);
              int s = a2 ? __builtin_ctz(im) : 0;
              if (a2) im &= im - 1;
              unsigned dvb = (unsigned)__shfl((int)__float_as_uint(d2), gbase + s);
              int ov = __shfl(oi, gbase + s);
              if (a2) insert(mapf_u(dvb), (unsigned)ov);
            }
            updT();
          }
        }
      }
    }
    const float big = 1e30f;
    float dxlo = (cx-R <= 0)      ? big : (qx - (lox + (float)(cx-R)*cwx));
    float dxhi = (cx+R >= GRES-1) ? big : ((lox + (float)(cx+R+1)*cwx) - qx);
    float dylo = (cy-R <= 0)      ? big : (qy - (loy + (float)(cy-R)*cwy));
    float dyhi = (cy+R >= GRES-1) ? big : ((loy + (float)(cy+R+1)*cwy) - qy);
    float dzlo = (cz-R <= 0)      ? big : (qz - (loz + (float)(cz-R)*cwz));
    float dzhi = (cz+R >= GRES-1) ? big : ((loz + (float)(cz+R+1)*cwz) - qz);
    float dmin = fminf(fminf(fminf(dxlo,dxhi), fminf(dylo,dyhi)), fminf(dzlo,dzhi));
    bool full = dmin >= 1e29f;
    dmin = fmaxf(dmin, 0.0f);
    float dmin2 = dmin*dmin;
    bool stop = full || (Tf + 1e-4f + Tf*1e-5f < dmin2);
    gdone = gdone || stop;
    if (__all(gdone)) break;
  }
  idxout[(((size_t)b<<13) + orig)*KNNK + sl] = (int)klo;
}

// ---------------- fused transform: 512 thr / 16 points, dual-buffer + gll + seq tiles ----------------
__global__ __launch_bounds__(512, 2) void fused_kernel(
    const float* __restrict__ x, const float* __restrict__ pos,
    const float* __restrict__ bq, const float* __restrict__ bk,
    const float* __restrict__ bv, const float* __restrict__ Wp1,
    const float* __restrict__ bp1, const float* __restrict__ bp2,
    const float* __restrict__ bg1, const float* __restrict__ bg2,
    const int* __restrict__ idxws, const unsigned short* __restrict__ wt,
    const unsigned short* __restrict__ xbf,
    float* __restrict__ out)
{
  extern __shared__ char smem[];
  char* Sbase = smem;                                        // weight slot S: 32768 B
  char* Tbase = smem + 32768;                                // weight slot T / per-wave tiles: 32768 B
  float* blds = (float*)(smem + 65536);                      // 1280 f32 = 5120 B
  float* q_lds = (float*)(smem + 70656);                     // [16][128] f32 = 8192 B (total 78848)

  const int tid = threadIdx.x;
  const int lane = tid & 63, w = tid >> 6;                   // w = 0..7
  const int r = lane & 15, grp = lane >> 4;
  const int pbase = blockIdx.x * 16;
  const int b = pbase >> 13;

  auto gll = [&](int s, char* dst){
#pragma unroll
    for (int k = 0; k < 4; ++k){
      int c = w*4 + k;
      unsigned short* g = const_cast<unsigned short*>(wt) + (size_t)s*WELEMF + c*512 + lane*8;
      __builtin_amdgcn_global_load_lds(
        (const __attribute__((address_space(1))) void*)g,
        (__attribute__((address_space(3))) void*)(dst + c*1024), 16, 0, 0);
    }
  };
  auto ldS = [&](int ct, int kk) -> s16x8 {
    return *(const s16x8*)&((unsigned short*)Sbase)[((ct*4 + kk)*64 + lane)*8];
  };
  auto ldT = [&](int ct, int kk) -> s16x8 {
    return *(const s16x8*)&((unsigned short*)Tbase)[((ct*4 + kk)*64 + lane)*8];
  };

  gll(0, Sbase);   // Wq  -> S  (cold)
  gll(3, Tbase);   // Wp2 -> T  (cold)

  for (int e = tid; e < 1280; e += 512){
    float v;
    if      (e < 128)  v = bq[e];
    else if (e < 256)  v = bk[e-128];
    else if (e < 384)  v = bv[e-256];
    else if (e < 512)  v = bp2[e-384];
    else if (e < 640)  v = bg1[e-512];
    else if (e < 768)  v = bg2[e-640];
    else if (e < 896)  v = bp1[e-768];
    else               v = Wp1[e-896];
    blds[e] = v;
  }
  int nbr[2]; float relx[2], rely[2], relz[2];
#pragma unroll
  for (int j = 0; j < 2; ++j){
    int gp = pbase + w*2 + j;
    nbr[j] = idxws[(size_t)gp*KNNK + r];
    const float* pq = pos + (size_t)gp*3;
    const float* pn = pos + ((size_t)b*NPTS + nbr[j])*3;
    relx[j] = pq[0]-pn[0]; rely[j] = pq[1]-pn[1]; relz[j] = pq[2]-pn[2];
  }
  s16x8 qa[4];
  if (xbf){
    const unsigned short* xr = xbf + (size_t)(pbase + r)*CDIM;
#pragma unroll
    for (int kk = 0; kk < 4; ++kk) qa[kk] = *(const s16x8*)&xr[kk*32 + grp*8];
  } else {
    const float* xr = x + (size_t)(pbase + r)*CDIM;
#pragma unroll
    for (int kk = 0; kk < 4; ++kk) qa[kk] = cvt8(xr + kk*32 + grp*8);
  }
  __syncthreads();   // Wq(S), Wp2(T), blds visible

  // ---- q = x@Wq + bq from S: wave w computes column tile ct = w ----
  {
    f32x4 qacc = (f32x4){0.f,0.f,0.f,0.f};
#pragma unroll
    for (int kk = 0; kk < 4; ++kk)
      qacc = __builtin_amdgcn_mfma_f32_16x16x32_bf16(qa[kk], ldS(w,kk), qacc, 0,0,0);
    int col = w*16 + r;
#pragma unroll
    for (int jj = 0; jj < 4; ++jj){
      int row = grp*4 + jj;
      q_lds[row*CDIM + col] = qacc[jj] + blds[col];
    }
  }
  // ---- pe1 = relu(rel@Wp1 + bp1) in A-frag layout ----
  s16x8 pf[2][4];
#pragma unroll
  for (int j = 0; j < 2; ++j)
#pragma unroll
    for (int kk = 0; kk < 4; ++kk){
      s16x8 f;
#pragma unroll
      for (int i = 0; i < 8; ++i){
        int kc = kk*32 + grp*8 + i;
        float s = relx[j]*blds[896+kc] + rely[j]*blds[1024+kc] + relz[j]*blds[1152+kc] + blds[768+kc];
        f[i] = (short)to_bf16(fmaxf(s, 0.f));
      }
      pf[j][kk] = f;
    }
  __syncthreads();   // Wq consumed; q_lds visible
  gll(1, Sbase);     // -Wk -> S, hides under pe1@Wp2 MFMAs

  f32x4 at[2][8], av[2][8];
#pragma unroll
  for (int j=0;j<2;++j)
#pragma unroll
    for (int ct=0;ct<8;++ct) at[j][ct] = (f32x4){0.f,0.f,0.f,0.f};
#pragma unroll
  for (int ct=0;ct<8;++ct)
#pragma unroll
    for (int kk=0;kk<4;++kk){
      s16x8 bw = ldT(ct,kk);
#pragma unroll
      for (int j=0;j<2;++j)
        at[j][ct] = __builtin_amdgcn_mfma_f32_16x16x32_bf16(pf[j][kk], bw, at[j][ct], 0,0,0);
    }
  s16x8 nf[2][4];
  if (xbf){
#pragma unroll
    for (int j=0;j<2;++j){
      const unsigned short* xr = xbf + ((size_t)b*NPTS + nbr[j])*CDIM;
#pragma unroll
      for (int kk=0;kk<4;++kk)
        nf[j][kk] = *(const s16x8*)&xr[kk*32 + grp*8];
    }
  } else {
#pragma unroll
    for (int j=0;j<2;++j)
#pragma unroll
      for (int kk=0;kk<4;++kk)
        nf[j][kk] = cvt8(x + ((size_t)b*NPTS + nbr[j])*CDIM + kk*32 + grp*8);
  }

  __syncthreads();   // Wp2 consumed; -Wk visible
  gll(2, Tbase);     // Wv -> T, hides under nf@(-Wk) MFMAs
#pragma unroll
  for (int j=0;j<2;++j)
#pragma unroll
    for (int ct=0;ct<8;++ct) av[j][ct] = at[j][ct];
#pragma unroll
  for (int ct=0;ct<8;++ct)
#pragma unroll
    for (int kk=0;kk<4;++kk){
      s16x8 bw = ldS(ct,kk);
#pragma unroll
      for (int j=0;j<2;++j) at[j][ct] = __builtin_amdgcn_mfma_f32_16x16x32_bf16(nf[j][kk], bw, at[j][ct], 0,0,0);
    }
  __syncthreads();   // -Wk consumed; Wv visible
  gll(4, Sbase);     // Wg1 -> S, hides under nf@Wv MFMAs
#pragma unroll
  for (int ct=0;ct<8;++ct)
#pragma unroll
    for (int kk=0;kk<4;++kk){
      s16x8 bw = ldT(ct,kk);
#pragma unroll
      for (int j=0;j<2;++j) av[j][ct] = __builtin_amdgcn_mfma_f32_16x16x32_bf16(nf[j][kk], bw, av[j][ct], 0,0,0);
    }
  // t = (q - k + pe) * scale
#pragma unroll
  for (int j=0;j<2;++j){
    int prow = (w*2+j)*CDIM;
#pragma unroll
    for (int ct=0;ct<8;++ct){
      int col = ct*16+r;
      float add = q_lds[prow+col] + blds[384+col] - blds[128+col];
#pragma unroll
      for (int jj=0;jj<4;++jj) at[j][ct][jj] = (at[j][ct][jj] + add)*SCALE;
    }
  }
  __syncthreads();   // Wv consumed (T freed for per-wave tiles); Wg1 visible

  // ---- gating MLP: per-wave private 4KB tile, points processed sequentially ----
  unsigned short* tj = (unsigned short*)Tbase + w*2048;      // 8 waves x 4KB = 32KB
  s16x8 tf[2][4];
#pragma unroll
  for (int j=0;j<2;++j){
#pragma unroll
    for (int ct=0;ct<8;++ct){
      int base = (ct>>1)*512 + ((ct&1)*2 + (r>>3))*128 + (r&7);
#pragma unroll
      for (int jj=0;jj<4;++jj)
        tj[base + (grp*4+jj)*8] = to_bf16(at[j][ct][jj]);
    }
#pragma unroll
    for (int kk=0;kk<4;++kk)
      tf[j][kk] = *(const s16x8*)&tj[(kk*64 + lane)*8];
  }
  f32x4 hacc[2][8];
#pragma unroll
  for (int j=0;j<2;++j)
#pragma unroll
    for (int ct=0;ct<8;++ct) hacc[j][ct] = (f32x4){0.f,0.f,0.f,0.f};
#pragma unroll
  for (int ct=0;ct<8;++ct)
#pragma unroll
    for (int kk=0;kk<4;++kk){
      s16x8 bw = ldS(ct,kk);
#pragma unroll
      for (int j=0;j<2;++j)
        hacc[j][ct] = __builtin_amdgcn_mfma_f32_16x16x32_bf16(tf[j][kk], bw, hacc[j][ct], 0,0,0);
    }
  __syncthreads();   // Wg1 consumed
  gll(5, Sbase);     // Wg2 -> S, hides under relu tile write/read
  s16x8 hf[2][4];
#pragma unroll
  for (int j=0;j<2;++j){
#pragma unroll
    for (int ct=0;ct<8;++ct){
      int base = (ct>>1)*512 + ((ct&1)*2 + (r>>3))*128 + (r&7);
      int col = ct*16+r; float bb = blds[512+col];
#pragma unroll
      for (int jj=0;jj<4;++jj)
        tj[base + (grp*4+jj)*8] = to_bf16(fmaxf(hacc[j][ct][jj]+bb, 0.f));
    }
#pragma unroll
    for (int kk=0;kk<4;++kk)
      hf[j][kk] = *(const s16x8*)&tj[(kk*64 + lane)*8];
  }
  __syncthreads();   // Wg2 visible
  f32x4 gacc[2][8];
#pragma unroll
  for (int j=0;j<2;++j)
#pragma unroll
    for (int ct=0;ct<8;++ct) gacc[j][ct] = (f32x4){0.f,0.f,0.f,0.f};
#pragma unroll
  for (int ct=0;ct<8;++ct)
#pragma unroll
    for (int kk=0;kk<4;++kk){
      s16x8 bw = ldS(ct,kk);
#pragma unroll
      for (int j=0;j<2;++j)
        gacc[j][ct] = __builtin_amdgcn_mfma_f32_16x16x32_bf16(hf[j][kk], bw, gacc[j][ct], 0,0,0);
    }
#pragma unroll
  for (int j=0;j<2;++j){
#pragma unroll
    for (int ct=0;ct<8;++ct){
      int col = ct*16+r;
      float gb = blds[640+col];
      float g0v = gacc[j][ct][0]+gb, g1v = gacc[j][ct][1]+gb;
      float g2v = gacc[j][ct][2]+gb, g3v = gacc[j][ct][3]+gb;
      float mx = fmaxf(fmaxf(g0v,g1v), fmaxf(g2v,g3v));
      mx = fmaxf(mx, __shfl_xor(mx,16));
      mx = fmaxf(mx, __shfl_xor(mx,32));
      float e0=__expf(g0v-mx), e1=__expf(g1v-mx), e2=__expf(g2v-mx), e3=__expf(g3v-mx);
      float vb = blds[256+col] + blds[384+col];
      float ss = e0+e1+e2+e3;
      float oo = e0*(av[j][ct][0]+vb) + e1*(av[j][ct][1]+vb)
               + e2*(av[j][ct][2]+vb) + e3*(av[j][ct][3]+vb);
      ss += __shfl_xor(ss,16); ss += __shfl_xor(ss,32);
      oo += __shfl_xor(oo,16); oo += __shfl_xor(oo,32);
      if (grp == 0) out[(size_t)(pbase + w*2 + j)*CDIM + col] = oo/ss;
    }
  }
}

extern "C" void kernel_launch(void* const* d_in, const int* in_sizes, int n_in,
                              void* d_out, int out_size, void* d_ws, size_t ws_size,
                              hipStream_t stream)
{
  const float* x    = (const float*)d_in[0];
  const float* pos  = (const float*)d_in[1];
  const float* Wq   = (const float*)d_in[2];
  const float* bq   = (const float*)d_in[3];
  const float* Wk   = (const float*)d_in[4];
  const float* bk   = (const float*)d_in[5];
  const float* Wv   = (const float*)d_in[6];
  const float* bv   = (const float*)d_in[7];
  const float* Wp1  = (const float*)d_in[8];
  const float* bp1  = (const float*)d_in[9];
  const float* Wp2  = (const float*)d_in[10];
  const float* bp2  = (const float*)d_in[11];
  const float* Wg1  = (const float*)d_in[12];
  const float* bg1  = (const float*)d_in[13];
  const float* Wg2  = (const float*)d_in[14];
  const float* bg2  = (const float*)d_in[15];
  float* out = (float*)d_out;

  char* ws = (char*)d_ws;
  int*            idxs   = (int*)ws;                          // 1,048,576
  unsigned short* wt     = (unsigned short*)(ws + 1048576);   //   196,608 (frag layout)
  float4*         spos4  = (float4*)(ws + 1519616);           //   262,144
  int*            starts = (int*)(ws + 2174976);              //    32,776
  unsigned*       bbox   = (unsigned*)(ws + 2699520);         //        48
  const size_t XBF_OFF = 2699776;
  const size_t XBF_SZ  = (size_t)2*NPTS*CDIM*2;               // 4,194,304
  unsigned short* xbf = (ws_size >= XBF_OFF + XBF_SZ) ? (unsigned short*)(ws + XBF_OFF) : nullptr;

  hipFuncSetAttribute((const void*)fused_kernel,
                      hipFuncAttributeMaxDynamicSharedMemorySize, FLDS_BYTES);

  setup_kernel<<<xbf ? 354 : 98, 1024, 0, stream>>>(pos, spos4, starts, bbox,
                                                    Wq, Wk, Wv, Wp2, Wg1, Wg2, x, wt, xbf);
  knn_grid_kernel<<<1024, 256, 0, stream>>>(spos4, starts, bbox, idxs);
  fused_kernel<<<1024, 512, FLDS_BYTES, stream>>>(x, pos, bq, bk, bv, Wp1, bp1, bp2,
                                                  bg1, bg2, idxs, wt, xbf, out);
}

// Round 20
// 181.535 us; speedup vs baseline: 1.3608x; 1.0001x over previous
//
#include <hip/hip_runtime.h>
#include <hip/hip_bf16.h>
#include <stdint.h>

#define NPTS 8192
#define CDIM 128
#define KNNK 16
#define WELEMF 16384               // frag-layout elems per weight image (128*128)
#define SCALE 0.08838834764831845f
#define FLDS_BYTES 78848
#define GRES 16
#define NCELL (GRES*GRES*GRES)

typedef __attribute__((ext_vector_type(4))) float f32x4;
typedef __attribute__((ext_vector_type(8))) short s16x8;

__device__ __forceinline__ unsigned short to_bf16(float f){
  union { __hip_bfloat16 h; unsigned short u; } v;
  v.h = __float2bfloat16(f);
  return v.u;
}

__device__ __forceinline__ s16x8 cvt8(const float* p){
  float4 lo = *(const float4*)p;
  float4 hi = *(const float4*)(p + 4);
  s16x8 f;
  f[0]=(short)to_bf16(lo.x); f[1]=(short)to_bf16(lo.y);
  f[2]=(short)to_bf16(lo.z); f[3]=(short)to_bf16(lo.w);
  f[4]=(short)to_bf16(hi.x); f[5]=(short)to_bf16(hi.y);
  f[6]=(short)to_bf16(hi.z); f[7]=(short)to_bf16(hi.w);
  return f;
}

__device__ __forceinline__ unsigned mapf_u(unsigned s){
  return s ^ (0x80000000u | (unsigned)(((int)s) >> 31));
}
__device__ __forceinline__ float unmapf_u(unsigned u){
  unsigned r = (u & 0x80000000u) ? (u ^ 0x80000000u) : ~u;
  return __uint_as_float(r);
}

// ---------------- setup: gridbuild (blocks 0-1) + weight/x bf16 prep (rest) ----------------
__global__ __launch_bounds__(1024) void setup_kernel(
    const float* __restrict__ pos, float4* __restrict__ spos4,
    int* __restrict__ starts, unsigned* __restrict__ bboxg,
    const float* __restrict__ Wq, const float* __restrict__ Wk,
    const float* __restrict__ Wv, const float* __restrict__ Wp2,
    const float* __restrict__ Wg1, const float* __restrict__ Wg2,
    const float* __restrict__ x,
    unsigned short* __restrict__ wt, unsigned short* __restrict__ xbf)
{
  __shared__ int cnt[NCELL];            // 16 KB (used by gridbuild blocks only)
  __shared__ int part[1024];            // 4 KB
  __shared__ unsigned bbl[6];
  const int t = threadIdx.x;

  if (blockIdx.x >= 2){
    int bid = blockIdx.x - 2;
    if (bid < 96){                      // weights -> frag-linear bf16 (96*1024 = 6*16384)
      int e = bid*1024 + t;
      int w = e >> 14, f = e & (WELEMF-1);
      int i = f & 7, ln = (f >> 3) & 63, kkct = f >> 9;
      int kk = kkct & 3, ct = kkct >> 2;
      int kdim = kk*32 + (ln >> 4)*8 + i, col = ct*16 + (ln & 15);
      const float* src = (w==0)?Wq:(w==1)?Wk:(w==2)?Wv:(w==3)?Wp2:(w==4)?Wg1:Wg2;
      float v = src[kdim*CDIM + col];
      if (w == 1) v = -v;               // store -Wk so k folds into the t accumulator
      wt[e] = to_bf16(v);
    } else if (xbf){                    // x -> bf16 (256*1024 vec8 = 2*8192*128 elems)
      size_t e = ((size_t)(bid - 96)*1024 + t) * 8;
      s16x8 v = cvt8(x + e);
      *(s16x8*)&xbf[e] = v;
    }
    return;
  }

  // ---- gridbuild: bbox + bin + scan + scatter for batch b ----
  const int b = blockIdx.x;
  for (int i = t; i < NCELL; i += 1024) cnt[i] = 0;
  if (t < 3) bbl[t] = 0xFFFFFFFFu;
  else if (t < 6) bbl[t] = 0u;
  __syncthreads();

  float4 p[8];
  unsigned mn0=~0u, mn1=~0u, mn2=~0u, mx0=0u, mx1=0u, mx2=0u;
#pragma unroll
  for (int i = 0; i < 8; ++i){
    int m = t + i*1024;
    const float* pp = pos + ((size_t)b*NPTS + m)*3;
    float xx = pp[0], yy = pp[1], zz = pp[2];
    float p2 = __fadd_rn(__fadd_rn(__fmul_rn(xx,xx), __fmul_rn(yy,yy)), __fmul_rn(zz,zz));
    p[i] = make_float4(xx, yy, zz, p2);
    unsigned ux = mapf_u(__float_as_uint(xx));
    unsigned uy = mapf_u(__float_as_uint(yy));
    unsigned uz = mapf_u(__float_as_uint(zz));
    mn0 = min(mn0, ux); mn1 = min(mn1, uy); mn2 = min(mn2, uz);
    mx0 = max(mx0, ux); mx1 = max(mx1, uy); mx2 = max(mx2, uz);
  }
#pragma unroll
  for (int off = 1; off < 64; off <<= 1){
    mn0 = min(mn0, (unsigned)__shfl_xor((int)mn0, off));
    mn1 = min(mn1, (unsigned)__shfl_xor((int)mn1, off));
    mn2 = min(mn2, (unsigned)__shfl_xor((int)mn2, off));
    mx0 = max(mx0, (unsigned)__shfl_xor((int)mx0, off));
    mx1 = max(mx1, (unsigned)__shfl_xor((int)mx1, off));
    mx2 = max(mx2, (unsigned)__shfl_xor((int)mx2, off));
  }
  if ((t & 63) == 0){
    atomicMin(&bbl[0], mn0); atomicMin(&bbl[1], mn1); atomicMin(&bbl[2], mn2);
    atomicMax(&bbl[3], mx0); atomicMax(&bbl[4], mx1); atomicMax(&bbl[5], mx2);
  }
  __syncthreads();
  const float lox = unmapf_u(bbl[0]), loy = unmapf_u(bbl[1]), loz = unmapf_u(bbl[2]);
  const float hix = unmapf_u(bbl[3]), hiy = unmapf_u(bbl[4]), hiz = unmapf_u(bbl[5]);

  int cid[8];
#pragma unroll
  for (int i = 0; i < 8; ++i){
    int ix = min(GRES-1, max(0, (int)((p[i].x - lox) * ((float)GRES/(hix-lox)))));
    int iy = min(GRES-1, max(0, (int)((p[i].y - loy) * ((float)GRES/(hiy-loy)))));
    int iz = min(GRES-1, max(0, (int)((p[i].z - loz) * ((float)GRES/(hiz-loz)))));
    cid[i] = (iz*GRES + iy)*GRES + ix;
    atomicAdd(&cnt[cid[i]], 1);
  }
  __syncthreads();
  // exclusive scan of 4096 counts: 4/thread + 1024-wide Hillis-Steele
  const int base = t*4;
  int c0 = cnt[base], c1 = cnt[base+1], c2 = cnt[base+2], c3 = cnt[base+3];
  part[t] = c0+c1+c2+c3;
  __syncthreads();
  for (int off = 1; off < 1024; off <<= 1){
    int v = (t >= off) ? part[t-off] : 0;
    __syncthreads();
    part[t] += v;
    __syncthreads();
  }
  int run = (t > 0) ? part[t-1] : 0;
  int* stb = starts + b*(NCELL+1);
  int r1 = run + c0, r2 = r1 + c1, r3 = r2 + c2;
  stb[base] = run; stb[base+1] = r1; stb[base+2] = r2; stb[base+3] = r3;
  if (t == 1023) stb[NCELL] = r3 + c3;
  cnt[base] = run; cnt[base+1] = r1; cnt[base+2] = r2; cnt[base+3] = r3;  // cursor
  __syncthreads();
  float4* spb = spos4 + ((size_t)b << 13);
#pragma unroll
  for (int i = 0; i < 8; ++i){
    int m = t + i*1024;
    int dst = atomicAdd(&cnt[cid[i]], 1);
    spb[dst] = make_float4(p[i].x, p[i].y, p[i].z, __uint_as_float((unsigned)m));
  }
  if (t < 6) bboxg[b*6 + t] = bbl[t];
}

// ---------------- kNN: 4 queries/wave (16-lane groups), sorted order, ring rows ----------------
__global__ __launch_bounds__(256) void knn_grid_kernel(
    const float4* __restrict__ spos4, const int* __restrict__ starts,
    const unsigned* __restrict__ bbox, int* __restrict__ idxout)
{
  const int tid = threadIdx.x, lane = tid & 63;
  const int sub = lane >> 4, sl = lane & 15, gbase = sub*16;
  const int w = tid >> 6;
  const int g = blockIdx.x*16 + w*4 + sub;          // 16 queries/block (sorted slots)
  const int b = g >> 13, n = g & (NPTS-1);
  const float4* sp = spos4 + ((size_t)b<<13);
  const int*    st = starts + b*(NCELL+1);

  const float4 q4 = sp[n];
  const int orig = __float_as_int(q4.w);
  const float qx = q4.x, qy = q4.y, qz = q4.z;
  const float q2 = __fadd_rn(__fadd_rn(__fmul_rn(qx,qx), __fmul_rn(qy,qy)), __fmul_rn(qz,qz));

  float lox = unmapf_u(bbox[b*6+0]), loy = unmapf_u(bbox[b*6+1]), loz = unmapf_u(bbox[b*6+2]);
  float hix = unmapf_u(bbox[b*6+3]), hiy = unmapf_u(bbox[b*6+4]), hiz = unmapf_u(bbox[b*6+5]);
  float cwx = (hix-lox)*(1.0f/GRES), cwy = (hiy-loy)*(1.0f/GRES), cwz = (hiz-loz)*(1.0f/GRES);
  int cx = min(GRES-1, max(0, (int)((qx - lox) * ((float)GRES/(hix-lox)))));
  int cy = min(GRES-1, max(0, (int)((qy - loy) * ((float)GRES/(hiy-loy)))));
  int cz = min(GRES-1, max(0, (int)((qz - loz) * ((float)GRES/(hiz-loz)))));

  unsigned khi = 0xFFFFFFFFu, klo = 0xFFFFFFFFu;    // per-group sorted list in lanes sl=0..15
  float Tf = __builtin_inff();

  auto insert = [&](unsigned ihi, unsigned ilo){
    unsigned phi = (unsigned)__builtin_amdgcn_update_dpp(0, (int)khi, 0x111, 0xF, 0xF, false);
    unsigned plo = (unsigned)__builtin_amdgcn_update_dpp(0, (int)klo, 0x111, 0xF, 0xF, false);
    bool gt  = (khi > ihi) || (khi == ihi && klo > ilo);
    bool pgt = (sl != 0) && ((phi > ihi) || (phi == ihi && plo > ilo));
    khi = gt ? (pgt ? phi : ihi) : khi;
    klo = gt ? (pgt ? plo : ilo) : klo;
  };
  auto updT = [&](){
    unsigned t15 = (unsigned)__shfl((int)khi, gbase + 15);
    Tf = (t15 >= 0xFF800000u) ? __builtin_inff() : unmapf_u(t15);
  };

  bool gdone = false;
  for (int R = 1; R <= GRES-1; ++R){
    const bool first = (R == 1);
    const int per = 8*R, w1 = 2*R-1;
    const int ntask = first ? 9 : (per + 2*w1*w1);
    for (int tb = 0; tb < ntask; tb += 16){
      int t = tb + sl;
      int dy = 0, dz = 0, gx0 = 0, gx1 = -1;
      bool valid = (!gdone) && (t < ntask);
      if (first){
        if (valid){ dy = t % 3 - 1; dz = t / 3 - 1; }
        gx0 = max(cx-1, 0); gx1 = min(cx+1, GRES-1);
      } else if (valid){
        if (t < per){                       // perimeter rows: full x-range
          int s2 = 2*(2*R+1);
          if (t < s2){ dz = (t < 2*R+1) ? -R : R; dy = t % (2*R+1) - R; }
          else { int u = t - s2; dy = (u & 1) ? R : -R; dz = (u >> 1) - (R-1); }
          gx0 = max(cx-R, 0); gx1 = min(cx+R, GRES-1);
        } else {                            // interior rows: two edge cells
          int i = t - per, ri = i >> 1;
          dy = ri % w1 - (R-1); dz = ri / w1 - (R-1);
          int gx = cx + ((i & 1) ? R : -R);
          gx0 = gx; gx1 = gx;
          valid = gx >= 0 && gx <= GRES-1;
        }
      }
      int gy = cy + dy, gz = cz + dz;
      valid = valid && gy >= 0 && gy < GRES && gz >= 0 && gz < GRES && gx0 <= gx1;
      int s0 = 0, s1 = 0;
      if (valid){ int cb = (gz*GRES + gy)*GRES; s0 = st[cb + gx0]; s1 = st[cb + gx1 + 1]; }
      unsigned long long bal = __ballot(valid && (s1 > s0));
      unsigned cm = (unsigned)((bal >> gbase) & 0xFFFFull);
      while (__any(cm != 0)){
        bool act = (cm != 0);
        int srow = act ? __builtin_ctz(cm) : 0;
        if (act) cm &= cm - 1;
        int cs = __shfl(s0, gbase + srow);
        int ce = __shfl(s1, gbase + srow);
        if (!act){ cs = 0; ce = 0; }
        for (int p0 = cs; p0 < ce; p0 += 16){
          int mm = p0 + sl;
          bool v = mm < ce;
          float4 c = v ? sp[mm] : make_float4(0.f,0.f,0.f,0.f);
          float c2  = __fadd_rn(__fadd_rn(__fmul_rn(c.x,c.x), __fmul_rn(c.y,c.y)), __fmul_rn(c.z,c.z));
          float dot = __builtin_fmaf(c.z, qz, __builtin_fmaf(c.y, qy, __fmul_rn(c.x, qx)));
          float d2  = __fsub_rn(__fadd_rn(q2, c2), __fadd_rn(dot, dot));
          int oi = __float_as_int(c.w);
          bool ins = v && (d2 <= Tf);
          unsigned long long ib = __ballot(ins);
          unsigned im = (unsigned)((ib >> gbase) & 0xFFFFull);
          if (__any(im != 0)){
            while (__any(im != 0)){
              bool a2 = (im != 0);
              int s = a2 ? __builtin_ctz(im) : 0;
              if (a2) im &= im - 1;
              unsigned dvb = (unsigned)__shfl((int)__float_as_uint(d2), gbase + s);
              int ov = __shfl(oi, gbase + s);
              if (a2) insert(mapf_u(dvb), (unsigned)ov);
            }
            updT();
          }
        }
      }
    }
    const float big = 1e30f;
    float dxlo = (cx-R <= 0)      ? big : (qx - (lox + (float)(cx-R)*cwx));
    float dxhi = (cx+R >= GRES-1) ? big : ((lox + (float)(cx+R+1)*cwx) - qx);
    float dylo = (cy-R <= 0)      ? big : (qy - (loy + (float)(cy-R)*cwy));
    float dyhi = (cy+R >= GRES-1) ? big : ((loy + (float)(cy+R+1)*cwy) - qy);
    float dzlo = (cz-R <= 0)      ? big : (qz - (loz + (float)(cz-R)*cwz));
    float dzhi = (cz+R >= GRES-1) ? big : ((loz + (float)(cz+R+1)*cwz) - qz);
    float dmin = fminf(fminf(fminf(dxlo,dxhi), fminf(dylo,dyhi)), fminf(dzlo,dzhi));
    bool full = dmin >= 1e29f;
    dmin = fmaxf(dmin, 0.0f);
    float dmin2 = dmin*dmin;
    bool stop = full || (Tf + 1e-4f + Tf*1e-5f < dmin2);
    gdone = gdone || stop;
    if (__all(gdone)) break;
  }
  idxout[(((size_t)b<<13) + orig)*KNNK + sl] = (int)klo;
}

// ---------------- fused transform: 512 thr / 16 points, dual-buffer + gll + swizzled tiles ----------------
__global__ __launch_bounds__(512, 2) void fused_kernel(
    const float* __restrict__ x, const float* __restrict__ pos,
    const float* __restrict__ bq, const float* __restrict__ bk,
    const float* __restrict__ bv, const float* __restrict__ Wp1,
    const float* __restrict__ bp1, const float* __restrict__ bp2,
    const float* __restrict__ bg1, const float* __restrict__ bg2,
    const int* __restrict__ idxws, const unsigned short* __restrict__ wt,
    const unsigned short* __restrict__ xbf,
    float* __restrict__ out)
{
  extern __shared__ char smem[];
  char* Sbase = smem;                                        // weight slot S: 32768 B
  char* Tbase = smem + 32768;                                // weight slot T / per-wave tiles: 32768 B
  float* blds = (float*)(smem + 65536);                      // 1280 f32 = 5120 B
  float* q_lds = (float*)(smem + 70656);                     // [16][128] f32 = 8192 B (total 78848)

  const int tid = threadIdx.x;
  const int lane = tid & 63, w = tid >> 6;                   // w = 0..7
  const int r = lane & 15, grp = lane >> 4;
  const int pbase = blockIdx.x * 16;
  const int b = pbase >> 13;

  auto gll = [&](int s, char* dst){
#pragma unroll
    for (int k = 0; k < 4; ++k){
      int c = w*4 + k;
      unsigned short* g = const_cast<unsigned short*>(wt) + (size_t)s*WELEMF + c*512 + lane*8;
      __builtin_amdgcn_global_load_lds(
        (const __attribute__((address_space(1))) void*)g,
        (__attribute__((address_space(3))) void*)(dst + c*1024), 16, 0, 0);
    }
  };
  auto ldS = [&](int ct, int kk) -> s16x8 {
    return *(const s16x8*)&((unsigned short*)Sbase)[((ct*4 + kk)*64 + lane)*8];
  };
  auto ldT = [&](int ct, int kk) -> s16x8 {
    return *(const s16x8*)&((unsigned short*)Tbase)[((ct*4 + kk)*64 + lane)*8];
  };

  gll(0, Sbase);   // Wq  -> S  (cold)
  gll(3, Tbase);   // Wp2 -> T  (cold)

  for (int e = tid; e < 1280; e += 512){
    float v;
    if      (e < 128)  v = bq[e];
    else if (e < 256)  v = bk[e-128];
    else if (e < 384)  v = bv[e-256];
    else if (e < 512)  v = bp2[e-384];
    else if (e < 640)  v = bg1[e-512];
    else if (e < 768)  v = bg2[e-640];
    else if (e < 896)  v = bp1[e-768];
    else               v = Wp1[e-896];
    blds[e] = v;
  }
  int nbr[2]; float relx[2], rely[2], relz[2];
#pragma unroll
  for (int j = 0; j < 2; ++j){
    int gp = pbase + w*2 + j;
    nbr[j] = idxws[(size_t)gp*KNNK + r];
    const float* pq = pos + (size_t)gp*3;
    const float* pn = pos + ((size_t)b*NPTS + nbr[j])*3;
    relx[j] = pq[0]-pn[0]; rely[j] = pq[1]-pn[1]; relz[j] = pq[2]-pn[2];
  }
  s16x8 qa[4];
  if (xbf){
    const unsigned short* xr = xbf + (size_t)(pbase + r)*CDIM;
#pragma unroll
    for (int kk = 0; kk < 4; ++kk) qa[kk] = *(const s16x8*)&xr[kk*32 + grp*8];
  } else {
    const float* xr = x + (size_t)(pbase + r)*CDIM;
#pragma unroll
    for (int kk = 0; kk < 4; ++kk) qa[kk] = cvt8(xr + kk*32 + grp*8);
  }
  __syncthreads();   // Wq(S), Wp2(T), blds visible

  // ---- q = x@Wq + bq from S: wave w computes column tile ct = w ----
  {
    f32x4 qacc = (f32x4){0.f,0.f,0.f,0.f};
#pragma unroll
    for (int kk = 0; kk < 4; ++kk)
      qacc = __builtin_amdgcn_mfma_f32_16x16x32_bf16(qa[kk], ldS(w,kk), qacc, 0,0,0);
    int col = w*16 + r;
#pragma unroll
    for (int jj = 0; jj < 4; ++jj){
      int row = grp*4 + jj;
      q_lds[row*CDIM + col] = qacc[jj] + blds[col];
    }
  }
  // ---- pe1 = relu(rel@Wp1 + bp1) in A-frag layout ----
  s16x8 pf[2][4];
#pragma unroll
  for (int j = 0; j < 2; ++j)
#pragma unroll
    for (int kk = 0; kk < 4; ++kk){
      s16x8 f;
#pragma unroll
      for (int i = 0; i < 8; ++i){
        int kc = kk*32 + grp*8 + i;
        float s = relx[j]*blds[896+kc] + rely[j]*blds[1024+kc] + relz[j]*blds[1152+kc] + blds[768+kc];
        f[i] = (short)to_bf16(fmaxf(s, 0.f));
      }
      pf[j][kk] = f;
    }
  __syncthreads();   // Wq consumed; q_lds visible
  gll(1, Sbase);     // -Wk -> S, hides under pe1@Wp2 MFMAs

  f32x4 at[2][8], av[2][8];
#pragma unroll
  for (int j=0;j<2;++j)
#pragma unroll
    for (int ct=0;ct<8;++ct) at[j][ct] = (f32x4){0.f,0.f,0.f,0.f};
#pragma unroll
  for (int ct=0;ct<8;++ct)
#pragma unroll
    for (int kk=0;kk<4;++kk){
      s16x8 bw = ldT(ct,kk);
#pragma unroll
      for (int j=0;j<2;++j)
        at[j][ct] = __builtin_amdgcn_mfma_f32_16x16x32_bf16(pf[j][kk], bw, at[j][ct], 0,0,0);
    }
  s16x8 nf[2][4];
  if (xbf){
#pragma unroll
    for (int j=0;j<2;++j){
      const unsigned short* xr = xbf + ((size_t)b*NPTS + nbr[j])*CDIM;
#pragma unroll
      for (int kk=0;kk<4;++kk)
        nf[j][kk] = *(const s16x8*)&xr[kk*32 + grp*8];
    }
  } else {
#pragma unroll
    for (int j=0;j<2;++j)
#pragma unroll
      for (int kk=0;kk<4;++kk)
        nf[j][kk] = cvt8(x + ((size_t)b*NPTS + nbr[j])*CDIM + kk*32 + grp*8);
  }

  __syncthreads();   // Wp2 consumed; -Wk visible
  gll(2, Tbase);     // Wv -> T, hides under nf@(-Wk) MFMAs
#pragma unroll
  for (int j=0;j<2;++j)
#pragma unroll
    for (int ct=0;ct<8;++ct) av[j][ct] = at[j][ct];
#pragma unroll
  for (int ct=0;ct<8;++ct)
#pragma unroll
    for (int kk=0;kk<4;++kk){
      s16x8 bw = ldS(ct,kk);
#pragma unroll
      for (int j=0;j<2;++j) at[j][ct] = __builtin_amdgcn_mfma_f32_16x16x32_bf16(nf[j][kk], bw, at[j][ct], 0,0,0);
    }
  __syncthreads();   // -Wk consumed; Wv visible
  gll(4, Sbase);     // Wg1 -> S, hides under nf@Wv MFMAs
#pragma unroll
  for (int ct=0;ct<8;++ct)
#pragma unroll
    for (int kk=0;kk<4;++kk){
      s16x8 bw = ldT(ct,kk);
#pragma unroll
      for (int j=0;j<2;++j) av[j][ct] = __builtin_amdgcn_mfma_f32_16x16x32_bf16(nf[j][kk], bw, av[j][ct], 0,0,0);
    }
  // t = (q - k + pe) * scale
#pragma unroll
  for (int j=0;j<2;++j){
    int prow = (w*2+j)*CDIM;
#pragma unroll
    for (int ct=0;ct<8;++ct){
      int col = ct*16+r;
      float add = q_lds[prow+col] + blds[384+col] - blds[128+col];
#pragma unroll
      for (int jj=0;jj<4;++jj) at[j][ct][jj] = (at[j][ct][jj] + add)*SCALE;
    }
  }
  __syncthreads();   // Wv consumed (T freed for per-wave tiles); Wg1 visible

  // ---- gating MLP: per-wave private 4KB tile, XOR-swizzled granules ----
  // granule g (16B units within wave tile); swizzle g' = g ^ ((g>>4)&7), applied
  // consistently on write+read -> bijective -> values identical, banks spread.
  unsigned short* tj = (unsigned short*)Tbase + w*2048;      // 8 waves x 4KB = 32KB
  s16x8 tf[2][4];
#pragma unroll
  for (int j=0;j<2;++j){
#pragma unroll
    for (int ct=0;ct<8;++ct){
      int gb = (ct>>1)*64 + ((ct&1)*2 + (r>>3))*16;         // granule base (mult of 16)
      int xo = (gb >> 4) & 7;
#pragma unroll
      for (int jj=0;jj<4;++jj){
        int gidx = (gb + grp*4 + jj) ^ xo;
        tj[gidx*8 + (r&7)] = to_bf16(at[j][ct][jj]);
      }
    }
#pragma unroll
    for (int kk=0;kk<4;++kk){
      int gidx = (kk*64 + lane) ^ ((kk*4 + grp) & 7);
      tf[j][kk] = *(const s16x8*)&tj[gidx*8];
    }
  }
  f32x4 hacc[2][8];
#pragma unroll
  for (int j=0;j<2;++j)
#pragma unroll
    for (int ct=0;ct<8;++ct) hacc[j][ct] = (f32x4){0.f,0.f,0.f,0.f};
#pragma unroll
  for (int ct=0;ct<8;++ct)
#pragma unroll
    for (int kk=0;kk<4;++kk){
      s16x8 bw = ldS(ct,kk);
#pragma unroll
      for (int j=0;j<2;++j)
        hacc[j][ct] = __builtin_amdgcn_mfma_f32_16x16x32_bf16(tf[j][kk], bw, hacc[j][ct], 0,0,0);
    }
  __syncthreads();   // Wg1 consumed
  gll(5, Sbase);     // Wg2 -> S, hides under relu tile write/read
  s16x8 hf[2][4];
#pragma unroll
  for (int j=0;j<2;++j){
#pragma unroll
    for (int ct=0;ct<8;++ct){
      int gb = (ct>>1)*64 + ((ct&1)*2 + (r>>3))*16;
      int xo = (gb >> 4) & 7;
      int col = ct*16+r; float bb = blds[512+col];
#pragma unroll
      for (int jj=0;jj<4;++jj){
        int gidx = (gb + grp*4 + jj) ^ xo;
        tj[gidx*8 + (r&7)] = to_bf16(fmaxf(hacc[j][ct][jj]+bb, 0.f));
      }
    }
#pragma unroll
    for (int kk=0;kk<4;++kk){
      int gidx = (kk*64 + lane) ^ ((kk*4 + grp) & 7);
      hf[j][kk] = *(const s16x8*)&tj[gidx*8];
    }
  }
  __syncthreads();   // Wg2 visible
  f32x4 gacc[2][8];
#pragma unroll
  for (int j=0;j<2;++j)
#pragma unroll
    for (int ct=0;ct<8;++ct) gacc[j][ct] = (f32x4){0.f,0.f,0.f,0.f};
#pragma unroll
  for (int ct=0;ct<8;++ct)
#pragma unroll
    for (int kk=0;kk<4;++kk){
      s16x8 bw = ldS(ct,kk);
#pragma unroll
      for (int j=0;j<2;++j)
        gacc[j][ct] = __builtin_amdgcn_mfma_f32_16x16x32_bf16(hf[j][kk], bw, gacc[j][ct], 0,0,0);
    }
#pragma unroll
  for (int j=0;j<2;++j){
#pragma unroll
    for (int ct=0;ct<8;++ct){
      int col = ct*16+r;
      float gb = blds[640+col];
      float g0v = gacc[j][ct][0]+gb, g1v = gacc[j][ct][1]+gb;
      float g2v = gacc[j][ct][2]+gb, g3v = gacc[j][ct][3]+gb;
      float mx = fmaxf(fmaxf(g0v,g1v), fmaxf(g2v,g3v));
      mx = fmaxf(mx, __shfl_xor(mx,16));
      mx = fmaxf(mx, __shfl_xor(mx,32));
      float e0=__expf(g0v-mx), e1=__expf(g1v-mx), e2=__expf(g2v-mx), e3=__expf(g3v-mx);
      float vb = blds[256+col] + blds[384+col];
      float ss = e0+e1+e2+e3;
      float oo = e0*(av[j][ct][0]+vb) + e1*(av[j][ct][1]+vb)
               + e2*(av[j][ct][2]+vb) + e3*(av[j][ct][3]+vb);
      ss += __shfl_xor(ss,16); ss += __shfl_xor(ss,32);
      oo += __shfl_xor(oo,16); oo += __shfl_xor(oo,32);
      if (grp == 0) out[(size_t)(pbase + w*2 + j)*CDIM + col] = oo/ss;
    }
  }
}

extern "C" void kernel_launch(void* const* d_in, const int* in_sizes, int n_in,
                              void* d_out, int out_size, void* d_ws, size_t ws_size,
                              hipStream_t stream)
{
  const float* x    = (const float*)d_in[0];
  const float* pos  = (const float*)d_in[1];
  const float* Wq   = (const float*)d_in[2];
  const float* bq   = (const float*)d_in[3];
  const float* Wk   = (const float*)d_in[4];
  const float* bk   = (const float*)d_in[5];
  const float* Wv   = (const float*)d_in[6];
  const float* bv   = (const float*)d_in[7];
  const float* Wp1  = (const float*)d_in[8];
  const float* bp1  = (const float*)d_in[9];
  const float* Wp2  = (const float*)d_in[10];
  const float* bp2  = (const float*)d_in[11];
  const float* Wg1  = (const float*)d_in[12];
  const float* bg1  = (const float*)d_in[13];
  const float* Wg2  = (const float*)d_in[14];
  const float* bg2  = (const float*)d_in[15];
  float* out = (float*)d_out;

  char* ws = (char*)d_ws;
  int*            idxs   = (int*)ws;                          // 1,048,576
  unsigned short* wt     = (unsigned short*)(ws + 1048576);   //   196,608 (frag layout)
  float4*         spos4  = (float4*)(ws + 1519616);           //   262,144
  int*            starts = (int*)(ws + 2174976);              //    32,776
  unsigned*       bbox   = (unsigned*)(ws + 2699520);         //        48
  const size_t XBF_OFF = 2699776;
  const size_t XBF_SZ  = (size_t)2*NPTS*CDIM*2;               // 4,194,304
  unsigned short* xbf = (ws_size >= XBF_OFF + XBF_SZ) ? (unsigned short*)(ws + XBF_OFF) : nullptr;

  hipFuncSetAttribute((const void*)fused_kernel,
                      hipFuncAttributeMaxDynamicSharedMemorySize, FLDS_BYTES);

  setup_kernel<<<xbf ? 354 : 98, 1024, 0, stream>>>(pos, spos4, starts, bbox,
                                                    Wq, Wk, Wv, Wp2, Wg1, Wg2, x, wt, xbf);
  knn_grid_kernel<<<1024, 256, 0, stream>>>(spos4, starts, bbox, idxs);
  fused_kernel<<<1024, 512, FLDS_BYTES, stream>>>(x, pos, bq, bk, bv, Wp1, bp1, bp2,
                                                  bg1, bg2, idxs, wt, xbf, out);
}